// Round 14
// baseline (798.901 us; speedup 1.0000x reference)
//
#include <hip/hip_runtime.h>
#include <hip/hip_bf16.h>
#include <math.h>

#define BB 8
#define NN 1000
#define EE 16000
#define ETOT 17000   // E + N self loops
#define TPRED 12
#define FEAT 13
#define INDIM 14
#define HEADS 8
#define HG 256
#define C1 2048      // HEADS*HG
#define GO 13
#define HID 64

typedef unsigned int  uint32;
typedef unsigned short ushort16;
typedef uint32 uvec4 __attribute__((ext_vector_type(4)));
typedef __fp16 hf2 __attribute__((ext_vector_type(2)));

union U32H2 { uint32 u; hf2 h; };
__device__ __forceinline__ hf2 u2h(uint32 u){ U32H2 c; c.u=u; return c.h; }
__device__ __forceinline__ uint32 h2u(hf2 h){ U32H2 c; c.h=h; return c.u; }

#if __has_builtin(__builtin_amdgcn_fdot2)
__device__ __forceinline__ float FDOT2(hf2 a, hf2 b, float c){
    return __builtin_amdgcn_fdot2(a, b, c, false);
}
#else
__device__ __forceinline__ float FDOT2(hf2 a, hf2 b, float c){
    return c + (float)a.x*(float)b.x + (float)a.y*(float)b.y;
}
#endif

__device__ __forceinline__ float lrelu(float v){ return v > 0.f ? v : 0.2f*v; }

__device__ __forceinline__ ushort16 f2bf(float f){
    union { float f; uint32 u; } v; v.f = f;
    uint32 r = v.u + 0x7FFFu + ((v.u >> 16) & 1u);   // RNE
    return (ushort16)(r >> 16);
}
__device__ __forceinline__ uint32 pack2(float lo, float hi){
    return (uint32)f2bf(lo) | ((uint32)f2bf(hi) << 16);
}
__device__ __forceinline__ void cvt2(uint32 u, float& lo, float& hi){
    union { uint32 u; float f; } a, b;
    a.u = u << 16; b.u = u & 0xFFFF0000u;
    lo = a.f; hi = b.f;
}
// f16 pair with RNE rounding
__device__ __forceinline__ uint32 pkh(float lo, float hi){
    hf2 h; h.x = (__fp16)lo; h.y = (__fp16)hi; return h2u(h);
}

// ---------------- setup: one merged prep kernel ----------------
// blocks [0,112): att1pre; [112,176): packW1; [176,180): att2pre; [180,204): packGRU
__global__ void k_prep(const float* W1, const float* a1s, const float* a1d,
                       const float* W2, const float* a2s, const float* a2d,
                       const float* Wih, const float* Whh,
                       float* Wsrc, float* Wdst, uint32* w1pk, uint32* w2pk,
                       uint32* WihP, uint32* WhhP){
    __shared__ float rs[4], rd[4];
    int bid = blockIdx.x, tid = threadIdx.x;
    if (bid < 112){
        int k = bid >> 3, h = bid & 7;
        float wv = W1[k*C1 + h*HG + tid];
        float ps = wv * a1s[h*HG + tid];
        float pd = wv * a1d[h*HG + tid];
        #pragma unroll
        for (int m=1;m<64;m<<=1){ ps += __shfl_xor(ps,m); pd += __shfl_xor(pd,m); }
        int w = tid>>6;
        if ((tid&63)==0){ rs[w]=ps; rd[w]=pd; }
        __syncthreads();
        if (tid==0){
            Wsrc[k*8+h] = rs[0]+rs[1]+rs[2]+rs[3];
            Wdst[k*8+h] = rd[0]+rd[1]+rd[2]+rd[3];
        }
    } else if (bid < 176){
        int i = (bid-112)*256 + tid;
        int c = i >> 3, kk = i & 7;
        float lo = (kk < 7) ? W1[(2*kk)*C1 + c]   : 0.f;
        float hi = (kk < 7) ? W1[(2*kk+1)*C1 + c] : 0.f;
        w1pk[i] = h2u(__builtin_amdgcn_cvt_pkrtz(lo, hi));
    } else if (bid < 180){
        int m = (bid-176)*256 + tid;
        if (m < C1/2){
            int c0 = 2*m, c1 = 2*m+1;
            float colA[16], colB[16];
            float ssA=0.f, ddA=0.f, ssB=0.f, ddB=0.f;
            #pragma unroll
            for (int j=0;j<GO;j++){
                float wA = W2[c0*GO+j], wB = W2[c1*GO+j];
                colA[j]=wA; colB[j]=wB;
                ssA += wA*a2s[j]; ddA += wA*a2d[j];
                ssB += wB*a2s[j]; ddB += wB*a2d[j];
            }
            colA[13]=ssA; colA[14]=ddA; colA[15]=0.f;
            colB[13]=ssB; colB[14]=ddB; colB[15]=0.f;
            #pragma unroll
            for (int j=0;j<16;j++)
                w2pk[m*16+j] = h2u(__builtin_amdgcn_cvt_pkrtz(colA[j], colB[j]));
        }
    } else {
        int i = (bid-180)*256 + tid;
        if (i < 192*14){
            int rr = i/14, c2 = i - rr*14;
            float lo = Wih[rr*27 + 2*c2];
            float hi = (2*c2+1 < 27) ? Wih[rr*27 + 2*c2 + 1] : 0.f;
            WihP[i] = pkh(lo, hi);
        }
        if (i < 192*32){
            int rr = i>>5, j2 = i&31;
            WhhP[i] = pkh(Whh[rr*64 + 2*j2], Whh[rr*64 + 2*j2 + 1]);
        }
    }
}

// init hn/xn/count AND compute step-0 scores + packed x (needs Wsrc/Wdst ready)
__global__ void k_init(const float* pm25, const float* feat,
                       const float* Wsrc, const float* Wdst,
                       float* hn, float* xn, int* count,
                       float* ssrc, float* sdst, uint32* xpk){
    int i = blockIdx.x*blockDim.x + threadIdx.x;
    if (i < BB*NN*HID) hn[i] = 0.f;
    if (i < NN) count[i] = 0;
    if (i < BB*NN){
        int b = i/NN, n = i%NN;
        float x[INDIM];
        x[0] = pm25[(b*8 + 7)*NN + n];
        xn[i] = x[0];
        const float* fp = feat + ((size_t)(b*20 + 8)*NN + n)*FEAT;
        #pragma unroll
        for (int k=0;k<FEAT;k++) x[k+1] = fp[k];
        #pragma unroll
        for (int h=0;h<8;h++){
            float ss=0.f, dd=0.f;
            #pragma unroll
            for (int k=0;k<INDIM;k++){ ss += x[k]*Wsrc[k*8+h]; dd += x[k]*Wdst[k*8+h]; }
            ssrc[i*8+h] = ss; sdst[i*8+h] = dd;
        }
        #pragma unroll
        for (int p=0;p<7;p++) xpk[i*8+p] = pack2(x[2*p], x[2*p+1]);
        xpk[i*8+7] = 0u;
    }
}

__global__ void k_count(const int* ei, int* count){
    int e = blockIdx.x*blockDim.x + threadIdx.x;
    if (e < ETOT){
        int dst = (e<EE) ? ei[EE+e] : (e-EE);
        atomicAdd(&count[dst], 1);
    }
}

__global__ void k_scan(const int* count, int* offs, int* cursor){
    __shared__ int s[1024];
    int tid = threadIdx.x;
    int myc = (tid<NN) ? count[tid] : 0;
    s[tid] = myc;
    __syncthreads();
    for (int d=1; d<1024; d<<=1){
        int v = (tid>=d) ? s[tid-d] : 0;
        __syncthreads();
        s[tid] += v;
        __syncthreads();
    }
    if (tid<NN){
        int off = s[tid] - myc;   // exclusive
        offs[tid] = off; cursor[tid] = off;
    }
    if (tid==NN-1) offs[NN] = s[tid];
}

__global__ void k_fill(const int* ei, int* cursor, int* csr_src){
    int e = blockIdx.x*blockDim.x + threadIdx.x;
    if (e < ETOT){
        int src = (e<EE) ? ei[e]    : (e-EE);
        int dst = (e<EE) ? ei[EE+e] : (e-EE);
        int pos = atomicAdd(&cursor[dst], 1);
        csr_src[pos] = src;
    }
}

// ---------------- per-step kernels ----------------

// per (b,dst), 1 wave: 8-head ONLINE softmax + aggregate 14-dim x in ONE pass.
// lane = slot*8 + h. Combine: max-butterfly + single rescale + sum-butterfly.
// Output packed f16: aggP[bn*64 + h*8 + p].
__global__ __launch_bounds__(64) void k_agg14(const uint32* xpk, const float* ssrc,
        const float* sdst, const int* offs, const int* csr, uint32* aggP){
    int lane = threadIdx.x;
    int blk = blockIdx.x;
    int b = blk & 7, dstn = blk >> 3;
    int bn = b*NN + dstn;
    int base = offs[dstn], deg = offs[dstn+1]-base;
    int slot = lane >> 3, h = lane & 7;
    float sdd = sdst[bn*8 + h];
    float m = -1e30f, d = 0.f;
    float acc[14];
    #pragma unroll
    for (int k=0;k<14;k++) acc[k]=0.f;
    for (int i=slot;i<deg;i+=8){
        int s = csr[base+i];
        float sc = lrelu(ssrc[(b*NN+s)*8+h]+sdd);
        float w;
        if (sc > m){
            float e = __expf(m - sc);
            d *= e;
            #pragma unroll
            for (int k=0;k<14;k++) acc[k] *= e;
            m = sc; w = 1.f;
        } else {
            w = __expf(sc - m);
        }
        d += w;
        const uint32* xp = xpk + (size_t)(b*NN+s)*8;
        #pragma unroll
        for (int p=0;p<7;p++){
            float x0,x1; cvt2(xp[p],x0,x1);
            acc[2*p]   += w*x0;
            acc[2*p+1] += w*x1;
        }
    }
    // combine across slots: max-butterfly, one rescale, sum-butterfly
    float mloc = m;
    m = fmaxf(m, __shfl_xor(m,8));
    m = fmaxf(m, __shfl_xor(m,16));
    m = fmaxf(m, __shfl_xor(m,32));
    float wr = __expf(mloc - m);
    d *= wr;
    #pragma unroll
    for (int k=0;k<14;k++) acc[k] *= wr;
    d += __shfl_xor(d,8); d += __shfl_xor(d,16); d += __shfl_xor(d,32);
    #pragma unroll
    for (int k=0;k<14;k++){
        acc[k] += __shfl_xor(acc[k],8);
        acc[k] += __shfl_xor(acc[k],16);
        acc[k] += __shfl_xor(acc[k],32);
    }
    if (slot==0){
        float rden = 1.f/d;
        uint32* ag = aggP + (size_t)bn*64 + h*8;
        #pragma unroll
        for (int p=0;p<7;p++)
            ag[p] = h2u(__builtin_amdgcn_cvt_pkrtz(acc[2*p]*rden, acc[2*p+1]*rden));
        ag[7] = 0u;
    }
}

// fused expand(14->2048) + bias + elu + contract(2048->16). grid 512.
// 2 nodes per round (8 rounds): halves barrier count, doubles dot-phase ILP.
__global__ __launch_bounds__(256,1) void k_expand(const uint32* aggP, const uint32* w1pk,
        const uint32* w2pk, const float* b1, float* h2o, float* s2s, float* s2d){
    int tid = threadIdx.x;
    int hh = tid >> 5;
    uint32 w1r[64];
    #pragma unroll
    for (int q=0;q<16;q++){
        uvec4 u = *(const uvec4*)(w1pk + tid*64 + 4*q);
        w1r[4*q]=u.x; w1r[4*q+1]=u.y; w1r[4*q+2]=u.z; w1r[4*q+3]=u.w;
    }
    uint32 w2r[64];
    #pragma unroll
    for (int q=0;q<16;q++){
        uvec4 u = *(const uvec4*)(w2pk + tid*64 + 4*q);
        w2r[4*q]=u.x; w2r[4*q+1]=u.y; w2r[4*q+2]=u.z; w2r[4*q+3]=u.w;
    }
    float b1r[8];
    #pragma unroll
    for (int j=0;j<8;j++) b1r[j] = b1[8*tid+j];
    __shared__ float sred0[256*17], sred1[256*17];
    __shared__ float red2a[64], red2b[64];
    for (int r = 0; r < 8; ++r){
        int idx0 = blockIdx.x + r*1024;
        int idx1 = idx0 + 512;
        bool ok1 = (idx1 < BB*NN);
        // node 0 dot-phase
        {
            const uvec4* ap = (const uvec4*)(aggP + (size_t)idx0*64 + hh*8);
            uvec4 u0 = ap[0], u1 = ap[1];
            hf2 agh[7];
            agh[0]=u2h(u0.x); agh[1]=u2h(u0.y); agh[2]=u2h(u0.z); agh[3]=u2h(u0.w);
            agh[4]=u2h(u1.x); agh[5]=u2h(u1.y); agh[6]=u2h(u1.z);
            float v[8];
            #pragma unroll
            for (int j=0;j<8;j++){
                float s = b1r[j];
                #pragma unroll
                for (int kk=0;kk<7;kk++) s = FDOT2(agh[kk], u2h(w1r[j*8+kk]), s);
                v[j] = s > 0.f ? s : __expf(s) - 1.f;
            }
            hf2 vp[4];
            #pragma unroll
            for (int q=0;q<4;q++) vp[q] = __builtin_amdgcn_cvt_pkrtz(v[2*q], v[2*q+1]);
            #pragma unroll
            for (int j=0;j<16;j++){
                float s = 0.f;
                #pragma unroll
                for (int q=0;q<4;q++) s = FDOT2(vp[q], u2h(w2r[q*16+j]), s);
                sred0[tid*17 + j] = s;
            }
        }
        // node 1 dot-phase
        if (ok1){
            const uvec4* ap = (const uvec4*)(aggP + (size_t)idx1*64 + hh*8);
            uvec4 u0 = ap[0], u1 = ap[1];
            hf2 agh[7];
            agh[0]=u2h(u0.x); agh[1]=u2h(u0.y); agh[2]=u2h(u0.z); agh[3]=u2h(u0.w);
            agh[4]=u2h(u1.x); agh[5]=u2h(u1.y); agh[6]=u2h(u1.z);
            float v[8];
            #pragma unroll
            for (int j=0;j<8;j++){
                float s = b1r[j];
                #pragma unroll
                for (int kk=0;kk<7;kk++) s = FDOT2(agh[kk], u2h(w1r[j*8+kk]), s);
                v[j] = s > 0.f ? s : __expf(s) - 1.f;
            }
            hf2 vp[4];
            #pragma unroll
            for (int q=0;q<4;q++) vp[q] = __builtin_amdgcn_cvt_pkrtz(v[2*q], v[2*q+1]);
            #pragma unroll
            for (int j=0;j<16;j++){
                float s = 0.f;
                #pragma unroll
                for (int q=0;q<4;q++) s = FDOT2(vp[q], u2h(w2r[q*16+j]), s);
                sred1[tid*17 + j] = s;
            }
        }
        __syncthreads();
        int j = tid & 15, g = tid >> 4;
        float s0 = 0.f, s1 = 0.f;
        #pragma unroll
        for (int i=0;i<16;i++){
            s0 += sred0[(g + 16*i)*17 + j];
            s1 += sred1[(g + 16*i)*17 + j];
        }
        s0 += __shfl_xor(s0, 16); s0 += __shfl_xor(s0, 32);
        s1 += __shfl_xor(s1, 16); s1 += __shfl_xor(s1, 32);
        int lane = tid & 63, w = tid >> 6;
        if (lane < 16){ red2a[w*16 + lane] = s0; red2b[w*16 + lane] = s1; }
        __syncthreads();
        if (tid < 15){
            float rv = red2a[tid] + red2a[16+tid] + red2a[32+tid] + red2a[48+tid];
            if (tid < GO)      h2o[idx0*GO + tid] = rv;
            else if (tid==13)  s2s[idx0] = rv;
            else               s2d[idx0] = rv;
        } else if (tid >= 16 && tid < 31 && ok1){
            int c = tid - 16;
            float rv = red2b[c] + red2b[16+c] + red2b[32+c] + red2b[48+c];
            if (c < GO)        h2o[idx1*GO + c] = rv;
            else if (c==13)    s2s[idx1] = rv;
            else               s2d[idx1] = rv;
        }
        __syncthreads();
    }
}

// fused: gat2agg (online pass; max-butterfly + single rescale + sum-butterfly)
// -> GRU (register-resident pre-packed f16 weights) -> fc_out -> next score.
__global__ __launch_bounds__(64,2) void k_tail(int t, int last,
        const float* feat, const int* offs, const int* csr,
        const float* h2, const float* s2src, const float* s2dst, const float* b2,
        const uint32* WihP, const uint32* WhhP, const float* bih, const float* bhh,
        const float* fcw, const float* fcb, const float* Wsrc, const float* Wdst,
        float* hn, float* xn, float* out,
        float* ssrc, float* sdst, uint32* xpk){
    int lane = threadIdx.x;
    // per-lane GRU weights: output unit = lane
    uint32 wih0[14], wih1[14], wih2[14];
    #pragma unroll
    for (int q=0;q<14;q++){
        wih0[q]=WihP[lane*14+q];
        wih1[q]=WihP[(64+lane)*14+q];
        wih2[q]=WihP[(128+lane)*14+q];
    }
    uint32 whh0[32], whh1[32], whh2[32];
    #pragma unroll
    for (int q=0;q<32;q++){
        whh0[q]=WhhP[lane*32+q];
        whh1[q]=WhhP[(64+lane)*32+q];
        whh2[q]=WhhP[(128+lane)*32+q];
    }
    float bi0=bih[lane], bi1=bih[64+lane], bi2=bih[128+lane];
    float bh0=bhh[lane], bh1=bhh[64+lane], bh2=bhh[128+lane];
    float fw = fcw[lane], fb = fcb[0];
    float b2r[GO];
    #pragma unroll
    for (int c=0;c<GO;c++) b2r[c] = b2[c];
    __shared__ uint32 hsP[32];
    for (int r=0;r<4;r++){
        int bn = blockIdx.x*4 + r;
        int b = bn/NN, n = bn - b*NN;
        // ---- GAT2 aggregation: single online pass ----
        int base = offs[n], deg = offs[n+1]-base;
        float sdd = s2dst[bn];
        float m = -1e30f, d = 0.f;
        float acc[GO];
        #pragma unroll
        for (int c=0;c<GO;c++) acc[c]=0.f;
        for (int e=lane;e<deg;e+=64){
            int s = csr[base+e];
            float sc = lrelu(s2src[b*NN+s] + sdd);
            float w;
            if (sc > m){
                float ee = __expf(m - sc);
                d *= ee;
                #pragma unroll
                for (int c=0;c<GO;c++) acc[c] *= ee;
                m = sc; w = 1.f;
            } else {
                w = __expf(sc - m);
            }
            d += w;
            const float* hr2 = h2 + (size_t)(b*NN+s)*GO;
            #pragma unroll
            for (int c=0;c<GO;c++) acc[c] += w*hr2[c];
        }
        // combine: max-butterfly + one rescale + sum-butterfly (broadcast)
        float mloc = m;
        #pragma unroll
        for (int st=1; st<64; st<<=1) m = fmaxf(m, __shfl_xor(m, st));
        float wr = __expf(mloc - m);
        d *= wr;
        #pragma unroll
        for (int c=0;c<GO;c++) acc[c] *= wr;
        #pragma unroll
        for (int st=1; st<64; st<<=1){
            d += __shfl_xor(d, st);
            #pragma unroll
            for (int c=0;c<GO;c++) acc[c] += __shfl_xor(acc[c], st);
        }
        float rdv = 1.f / d;
        // all lanes now hold g[c] = acc[c]*rdv + b2r[c]
        float xnv = xn[bn];
        const float* fp = feat + ((size_t)(b*20 + 8 + t)*NN + n)*FEAT;
        float ft[FEAT];
        #pragma unroll
        for (int k=0;k<FEAT;k++) ft[k] = fp[k];
        hf2 gx[14];
        #pragma unroll
        for (int p=0;p<6;p++)
            gx[p] = u2h(pkh(acc[2*p]*rdv+b2r[2*p], acc[2*p+1]*rdv+b2r[2*p+1]));
        gx[6] = u2h(pkh(acc[12]*rdv+b2r[12], xnv));
        #pragma unroll
        for (int p=0;p<6;p++)
            gx[7+p] = u2h(pkh(ft[2*p], ft[2*p+1]));
        gx[13] = u2h(pkh(ft[12], 0.f));
        // h state
        float hold = hn[bn*HID + lane];
        if (lane<32) hsP[lane] = pkh(hn[bn*HID + 2*lane], hn[bn*HID + 2*lane + 1]);
        __syncthreads();
        // ---- GRU via f16 dot2, register weights ----
        float ir = bi0, iz = bi1, inn = bi2;
        #pragma unroll
        for (int c2=0;c2<14;c2++){
            ir  = FDOT2(gx[c2], u2h(wih0[c2]), ir);
            iz  = FDOT2(gx[c2], u2h(wih1[c2]), iz);
            inn = FDOT2(gx[c2], u2h(wih2[c2]), inn);
        }
        float hr = bh0, hz = bh1, hnv = bh2;
        #pragma unroll
        for (int j2=0;j2<32;j2++){
            hf2 hv = u2h(hsP[j2]);
            hr  = FDOT2(hv, u2h(whh0[j2]), hr);
            hz  = FDOT2(hv, u2h(whh1[j2]), hz);
            hnv = FDOT2(hv, u2h(whh2[j2]), hnv);
        }
        float rg = 1.f/(1.f+__expf(-(ir+hr)));
        float zg = 1.f/(1.f+__expf(-(iz+hz)));
        float nv = tanhf(inn + rg*hnv);
        float hnew = (1.f - zg)*nv + zg*hold;
        hn[bn*HID+lane] = hnew;
        float xv = hnew * fw;
        #pragma unroll
        for (int mm=1;mm<64;mm<<=1) xv += __shfl_xor(xv,mm);
        float res = xv + fb;    // all lanes have it
        if (lane==0){
            xn[bn] = res;
            out[(b*TPRED + t)*NN + n] = res;
        }
        // ---- score + pack for step t+1 ----
        if (!last){
            const float* fp2 = feat + ((size_t)(b*20 + 9 + t)*NN + n)*FEAT;
            if (lane < 16){
                int h = lane & 7;
                const float* Wa = (lane<8) ? Wsrc : Wdst;
                float s = res * Wa[h];
                #pragma unroll
                for (int k=1;k<14;k++) s += fp2[k-1]*Wa[k*8+h];
                if (lane<8) ssrc[bn*8+h] = s; else sdst[bn*8+h] = s;
            } else if (lane < 23){
                int p = lane - 16;
                float lo = (p==0) ? res : fp2[2*p-1];
                float hi = fp2[2*p];
                xpk[bn*8+p] = pack2(lo, hi);
            } else if (lane == 23){
                xpk[bn*8+7] = 0u;
            }
        }
        __syncthreads();
    }
}

// ---------------- host ----------------

extern "C" void kernel_launch(void* const* d_in, const int* in_sizes, int n_in,
                              void* d_out, int out_size, void* d_ws, size_t ws_size,
                              hipStream_t stream){
    const float* pm25 = (const float*)d_in[0];
    const float* feat = (const float*)d_in[1];
    const int*   ei   = (const int*)  d_in[2];
    const float* W1   = (const float*)d_in[3];
    const float* a1s  = (const float*)d_in[4];
    const float* a1d  = (const float*)d_in[5];
    const float* b1   = (const float*)d_in[6];
    const float* W2   = (const float*)d_in[7];
    const float* a2s  = (const float*)d_in[8];
    const float* a2d  = (const float*)d_in[9];
    const float* b2   = (const float*)d_in[10];
    const float* Wih  = (const float*)d_in[11];
    const float* Whh  = (const float*)d_in[12];
    const float* bih  = (const float*)d_in[13];
    const float* bhh  = (const float*)d_in[14];
    const float* fcw  = (const float*)d_in[15];
    const float* fcb  = (const float*)d_in[16];
    float* out = (float*)d_out;

    float* f = (float*)d_ws;
    size_t o = 0;
    float* ssrc1 = f+o; o += (size_t)BB*NN*8;
    float* sdst1 = f+o; o += (size_t)BB*NN*8;
    uint32* aggP = (uint32*)(f+o); o += (size_t)BB*NN*64;  // packed f16 agg
    float* h2    = f+o; o += (size_t)BB*NN*GO + 8;
    float* s2s   = f+o; o += (size_t)BB*NN;
    float* s2d   = f+o; o += (size_t)BB*NN;
    float* hn    = f+o; o += (size_t)BB*NN*HID;
    float* xn    = f+o; o += (size_t)BB*NN;
    float* Wsrc  = f+o; o += INDIM*8;
    float* Wdst  = f+o; o += INDIM*8;
    uint32* xpk  = (uint32*)(f+o); o += (size_t)BB*NN*8;
    uint32* w1pk = (uint32*)(f+o); o += (size_t)C1*8;      // 64KB f16 pairs
    uint32* w2pk = (uint32*)(f+o); o += (size_t)(C1/2)*16; // 64KB f16 pairs
    uint32* WihP = (uint32*)(f+o); o += 192*14;
    uint32* WhhP = (uint32*)(f+o); o += 192*32;
    int* ibase  = (int*)(f+o);
    int* count  = ibase;
    int* cursor = ibase + NN;
    int* offs   = ibase + 2*NN;
    int* csr    = ibase + 2*NN + NN + 1;

    k_prep  <<<204, 256,0,stream>>>(W1, a1s, a1d, W2, a2s, a2d, Wih, Whh,
                                    Wsrc, Wdst, w1pk, w2pk, WihP, WhhP);
    k_init  <<<2000,256,0,stream>>>(pm25, feat, Wsrc, Wdst, hn, xn, count,
                                    ssrc1, sdst1, xpk);
    k_count <<<67,  256,0,stream>>>(ei, count);
    k_scan  <<<1,  1024,0,stream>>>(count, offs, cursor);
    k_fill  <<<67,  256,0,stream>>>(ei, cursor, csr);

    for (int t=0; t<TPRED; t++){
        k_agg14 <<<8000, 64,0,stream>>>(xpk, ssrc1, sdst1, offs, csr, aggP);
        k_expand<<<512, 256,0,stream>>>(aggP, w1pk, w2pk, b1, h2, s2s, s2d);
        k_tail  <<<2000, 64,0,stream>>>(t, (t==TPRED-1)?1:0, feat, offs, csr,
                                        h2, s2s, s2d, b2,
                                        WihP, WhhP, bih, bhh, fcw, fcb, Wsrc, Wdst,
                                        hn, xn, out, ssrc1, sdst1, xpk);
    }
}

// Round 15
// 778.548 us; speedup vs baseline: 1.0261x; 1.0261x over previous
//
#include <hip/hip_runtime.h>
#include <hip/hip_bf16.h>
#include <math.h>

#define BB 8
#define NN 1000
#define EE 16000
#define ETOT 17000   // E + N self loops
#define TPRED 12
#define FEAT 13
#define INDIM 14
#define HEADS 8
#define HG 256
#define C1 2048      // HEADS*HG
#define GO 13
#define HID 64

typedef unsigned int  uint32;
typedef unsigned short ushort16;
typedef uint32 uvec4 __attribute__((ext_vector_type(4)));
typedef __fp16 hf2 __attribute__((ext_vector_type(2)));

union U32H2 { uint32 u; hf2 h; };
__device__ __forceinline__ hf2 u2h(uint32 u){ U32H2 c; c.u=u; return c.h; }
__device__ __forceinline__ uint32 h2u(hf2 h){ U32H2 c; c.h=h; return c.u; }

#if __has_builtin(__builtin_amdgcn_fdot2)
__device__ __forceinline__ float FDOT2(hf2 a, hf2 b, float c){
    return __builtin_amdgcn_fdot2(a, b, c, false);
}
#else
__device__ __forceinline__ float FDOT2(hf2 a, hf2 b, float c){
    return c + (float)a.x*(float)b.x + (float)a.y*(float)b.y;
}
#endif

__device__ __forceinline__ float lrelu(float v){ return v > 0.f ? v : 0.2f*v; }

__device__ __forceinline__ ushort16 f2bf(float f){
    union { float f; uint32 u; } v; v.f = f;
    uint32 r = v.u + 0x7FFFu + ((v.u >> 16) & 1u);   // RNE
    return (ushort16)(r >> 16);
}
__device__ __forceinline__ uint32 pack2(float lo, float hi){
    return (uint32)f2bf(lo) | ((uint32)f2bf(hi) << 16);
}
__device__ __forceinline__ void cvt2(uint32 u, float& lo, float& hi){
    union { uint32 u; float f; } a, b;
    a.u = u << 16; b.u = u & 0xFFFF0000u;
    lo = a.f; hi = b.f;
}
// f16 pair with RNE rounding
__device__ __forceinline__ uint32 pkh(float lo, float hi){
    hf2 h; h.x = (__fp16)lo; h.y = (__fp16)hi; return h2u(h);
}

// ---------------- setup: one merged prep kernel ----------------
// blocks [0,112): att1pre; [112,176): packW1; [176,180): att2pre; [180,204): packGRU
__global__ void k_prep(const float* W1, const float* a1s, const float* a1d,
                       const float* W2, const float* a2s, const float* a2d,
                       const float* Wih, const float* Whh,
                       float* Wsrc, float* Wdst, uint32* w1pk, uint32* w2pk,
                       uint32* WihP, uint32* WhhP){
    __shared__ float rs[4], rd[4];
    int bid = blockIdx.x, tid = threadIdx.x;
    if (bid < 112){
        int k = bid >> 3, h = bid & 7;
        float wv = W1[k*C1 + h*HG + tid];
        float ps = wv * a1s[h*HG + tid];
        float pd = wv * a1d[h*HG + tid];
        #pragma unroll
        for (int m=1;m<64;m<<=1){ ps += __shfl_xor(ps,m); pd += __shfl_xor(pd,m); }
        int w = tid>>6;
        if ((tid&63)==0){ rs[w]=ps; rd[w]=pd; }
        __syncthreads();
        if (tid==0){
            Wsrc[k*8+h] = rs[0]+rs[1]+rs[2]+rs[3];
            Wdst[k*8+h] = rd[0]+rd[1]+rd[2]+rd[3];
        }
    } else if (bid < 176){
        int i = (bid-112)*256 + tid;
        int c = i >> 3, kk = i & 7;
        float lo = (kk < 7) ? W1[(2*kk)*C1 + c]   : 0.f;
        float hi = (kk < 7) ? W1[(2*kk+1)*C1 + c] : 0.f;
        w1pk[i] = h2u(__builtin_amdgcn_cvt_pkrtz(lo, hi));
    } else if (bid < 180){
        int m = (bid-176)*256 + tid;
        if (m < C1/2){
            int c0 = 2*m, c1 = 2*m+1;
            float colA[16], colB[16];
            float ssA=0.f, ddA=0.f, ssB=0.f, ddB=0.f;
            #pragma unroll
            for (int j=0;j<GO;j++){
                float wA = W2[c0*GO+j], wB = W2[c1*GO+j];
                colA[j]=wA; colB[j]=wB;
                ssA += wA*a2s[j]; ddA += wA*a2d[j];
                ssB += wB*a2s[j]; ddB += wB*a2d[j];
            }
            colA[13]=ssA; colA[14]=ddA; colA[15]=0.f;
            colB[13]=ssB; colB[14]=ddB; colB[15]=0.f;
            #pragma unroll
            for (int j=0;j<16;j++)
                w2pk[m*16+j] = h2u(__builtin_amdgcn_cvt_pkrtz(colA[j], colB[j]));
        }
    } else {
        int i = (bid-180)*256 + tid;
        if (i < 192*14){
            int rr = i/14, c2 = i - rr*14;
            float lo = Wih[rr*27 + 2*c2];
            float hi = (2*c2+1 < 27) ? Wih[rr*27 + 2*c2 + 1] : 0.f;
            WihP[i] = pkh(lo, hi);
        }
        if (i < 192*32){
            int rr = i>>5, j2 = i&31;
            WhhP[i] = pkh(Whh[rr*64 + 2*j2], Whh[rr*64 + 2*j2 + 1]);
        }
    }
}

// init hn/xn/count AND compute step-0 scores + packed x (needs Wsrc/Wdst ready)
__global__ void k_init(const float* pm25, const float* feat,
                       const float* Wsrc, const float* Wdst,
                       float* hn, float* xn, int* count,
                       float* ssrc, float* sdst, uint32* xpk){
    int i = blockIdx.x*blockDim.x + threadIdx.x;
    if (i < BB*NN*HID) hn[i] = 0.f;
    if (i < NN) count[i] = 0;
    if (i < BB*NN){
        int b = i/NN, n = i%NN;
        float x[INDIM];
        x[0] = pm25[(b*8 + 7)*NN + n];
        xn[i] = x[0];
        const float* fp = feat + ((size_t)(b*20 + 8)*NN + n)*FEAT;
        #pragma unroll
        for (int k=0;k<FEAT;k++) x[k+1] = fp[k];
        #pragma unroll
        for (int h=0;h<8;h++){
            float ss=0.f, dd=0.f;
            #pragma unroll
            for (int k=0;k<INDIM;k++){ ss += x[k]*Wsrc[k*8+h]; dd += x[k]*Wdst[k*8+h]; }
            ssrc[i*8+h] = ss; sdst[i*8+h] = dd;
        }
        #pragma unroll
        for (int p=0;p<7;p++) xpk[i*8+p] = pack2(x[2*p], x[2*p+1]);
        xpk[i*8+7] = 0u;
    }
}

__global__ void k_count(const int* ei, int* count){
    int e = blockIdx.x*blockDim.x + threadIdx.x;
    if (e < ETOT){
        int dst = (e<EE) ? ei[EE+e] : (e-EE);
        atomicAdd(&count[dst], 1);
    }
}

__global__ void k_scan(const int* count, int* offs, int* cursor){
    __shared__ int s[1024];
    int tid = threadIdx.x;
    int myc = (tid<NN) ? count[tid] : 0;
    s[tid] = myc;
    __syncthreads();
    for (int d=1; d<1024; d<<=1){
        int v = (tid>=d) ? s[tid-d] : 0;
        __syncthreads();
        s[tid] += v;
        __syncthreads();
    }
    if (tid<NN){
        int off = s[tid] - myc;   // exclusive
        offs[tid] = off; cursor[tid] = off;
    }
    if (tid==NN-1) offs[NN] = s[tid];
}

__global__ void k_fill(const int* ei, int* cursor, int* csr_src){
    int e = blockIdx.x*blockDim.x + threadIdx.x;
    if (e < ETOT){
        int src = (e<EE) ? ei[e]    : (e-EE);
        int dst = (e<EE) ? ei[EE+e] : (e-EE);
        int pos = atomicAdd(&cursor[dst], 1);
        csr_src[pos] = src;
    }
}

// ---------------- per-step kernels ----------------

// per (b,dst), 1 wave: 8-head ONLINE softmax + aggregate 14-dim x in ONE pass.
// lane = slot*8 + h. Flash-combine butterfly over slot bits (8,16,32).
// Output packed f16: aggP[bn*64 + h*8 + p].
__global__ __launch_bounds__(64) void k_agg14(const uint32* xpk, const float* ssrc,
        const float* sdst, const int* offs, const int* csr, uint32* aggP){
    int lane = threadIdx.x;
    int blk = blockIdx.x;
    int b = blk & 7, dstn = blk >> 3;
    int bn = b*NN + dstn;
    int base = offs[dstn], deg = offs[dstn+1]-base;
    int slot = lane >> 3, h = lane & 7;
    float sdd = sdst[bn*8 + h];
    float m = -1e30f, d = 0.f;
    float acc[14];
    #pragma unroll
    for (int k=0;k<14;k++) acc[k]=0.f;
    for (int i=slot;i<deg;i+=8){
        int s = csr[base+i];
        float sc = lrelu(ssrc[(b*NN+s)*8+h]+sdd);
        float w;
        if (sc > m){
            float e = __expf(m - sc);
            d *= e;
            #pragma unroll
            for (int k=0;k<14;k++) acc[k] *= e;
            m = sc; w = 1.f;
        } else {
            w = __expf(sc - m);
        }
        d += w;
        const uint32* xp = xpk + (size_t)(b*NN+s)*8;
        #pragma unroll
        for (int p=0;p<7;p++){
            float x0,x1; cvt2(xp[p],x0,x1);
            acc[2*p]   += w*x0;
            acc[2*p+1] += w*x1;
        }
    }
    // flash-combine across slots
    #pragma unroll
    for (int st=8; st<64; st<<=1){
        float m2 = __shfl_xor(m, st);
        float d2 = __shfl_xor(d, st);
        float mn = fmaxf(m, m2);
        float e1 = __expf(m - mn), e2 = __expf(m2 - mn);
        d = d*e1 + d2*e2;
        #pragma unroll
        for (int k=0;k<14;k++){
            float a2 = __shfl_xor(acc[k], st);
            acc[k] = acc[k]*e1 + a2*e2;
        }
        m = mn;
    }
    if (slot==0){
        float rden = 1.f/d;
        uint32* ag = aggP + (size_t)bn*64 + h*8;
        #pragma unroll
        for (int p=0;p<7;p++)
            ag[p] = h2u(__builtin_amdgcn_cvt_pkrtz(acc[2*p]*rden, acc[2*p+1]*rden));
        ag[7] = 0u;
    }
}

// fused expand(14->2048) + bias + elu + contract(2048->16). grid 512 (R9-proven).
// agg input packed f16 pairs (32B per thread-node).
__global__ __launch_bounds__(256,1) void k_expand(const uint32* aggP, const uint32* w1pk,
        const uint32* w2pk, const float* b1, float* h2o, float* s2s, float* s2d){
    int tid = threadIdx.x;
    int hh = tid >> 5;
    uint32 w1r[64];
    #pragma unroll
    for (int q=0;q<16;q++){
        uvec4 u = *(const uvec4*)(w1pk + tid*64 + 4*q);
        w1r[4*q]=u.x; w1r[4*q+1]=u.y; w1r[4*q+2]=u.z; w1r[4*q+3]=u.w;
    }
    uint32 w2r[64];
    #pragma unroll
    for (int q=0;q<16;q++){
        uvec4 u = *(const uvec4*)(w2pk + tid*64 + 4*q);
        w2r[4*q]=u.x; w2r[4*q+1]=u.y; w2r[4*q+2]=u.z; w2r[4*q+3]=u.w;
    }
    float b1r[8];
    #pragma unroll
    for (int j=0;j<8;j++) b1r[j] = b1[8*tid+j];
    __shared__ float sred[256*17];    // stride 17: conflict-free scalar writes
    __shared__ float red2[64];
    for (int idx = blockIdx.x; idx < BB*NN; idx += gridDim.x){
        const uvec4* ap = (const uvec4*)(aggP + (size_t)idx*64 + hh*8);
        uvec4 u0 = ap[0], u1 = ap[1];
        hf2 agh[7];
        agh[0]=u2h(u0.x); agh[1]=u2h(u0.y); agh[2]=u2h(u0.z); agh[3]=u2h(u0.w);
        agh[4]=u2h(u1.x); agh[5]=u2h(u1.y); agh[6]=u2h(u1.z);
        float v[8];
        #pragma unroll
        for (int j=0;j<8;j++){
            float s = b1r[j];
            #pragma unroll
            for (int kk=0;kk<7;kk++) s = FDOT2(agh[kk], u2h(w1r[j*8+kk]), s);
            v[j] = s > 0.f ? s : __expf(s) - 1.f;   // elu
        }
        hf2 vp[4];
        #pragma unroll
        for (int q=0;q<4;q++) vp[q] = __builtin_amdgcn_cvt_pkrtz(v[2*q], v[2*q+1]);
        #pragma unroll
        for (int j=0;j<16;j++){
            float s = 0.f;
            #pragma unroll
            for (int q=0;q<4;q++) s = FDOT2(vp[q], u2h(w2r[q*16+j]), s);
            sred[tid*17 + j] = s;
        }
        __syncthreads();
        int j = tid & 15, g = tid >> 4;
        float s = 0.f;
        #pragma unroll
        for (int i=0;i<16;i++) s += sred[(g + 16*i)*17 + j];
        s += __shfl_xor(s, 16);
        s += __shfl_xor(s, 32);
        int lane = tid & 63, w = tid >> 6;
        if (lane < 16) red2[w*16 + lane] = s;
        __syncthreads();
        if (tid < 15){
            float r = red2[tid] + red2[16+tid] + red2[32+tid] + red2[48+tid];
            if (tid < GO)      h2o[idx*GO + tid] = r;
            else if (tid==13)  s2s[idx] = r;
            else               s2d[idx] = r;
        }
        __syncthreads();
    }
}

// fused: gat2agg (ONE online-softmax pass + flash-combine butterfly)
// -> GRU (register-resident pre-packed f16 weights) -> fc_out -> next score.
__global__ __launch_bounds__(64,2) void k_tail(int t, int last,
        const float* feat, const int* offs, const int* csr,
        const float* h2, const float* s2src, const float* s2dst, const float* b2,
        const uint32* WihP, const uint32* WhhP, const float* bih, const float* bhh,
        const float* fcw, const float* fcb, const float* Wsrc, const float* Wdst,
        float* hn, float* xn, float* out,
        float* ssrc, float* sdst, uint32* xpk){
    int lane = threadIdx.x;
    // per-lane GRU weights: output unit = lane
    uint32 wih0[14], wih1[14], wih2[14];
    #pragma unroll
    for (int q=0;q<14;q++){
        wih0[q]=WihP[lane*14+q];
        wih1[q]=WihP[(64+lane)*14+q];
        wih2[q]=WihP[(128+lane)*14+q];
    }
    uint32 whh0[32], whh1[32], whh2[32];
    #pragma unroll
    for (int q=0;q<32;q++){
        whh0[q]=WhhP[lane*32+q];
        whh1[q]=WhhP[(64+lane)*32+q];
        whh2[q]=WhhP[(128+lane)*32+q];
    }
    float bi0=bih[lane], bi1=bih[64+lane], bi2=bih[128+lane];
    float bh0=bhh[lane], bh1=bhh[64+lane], bh2=bhh[128+lane];
    float fw = fcw[lane], fb = fcb[0];
    float b2r[GO];
    #pragma unroll
    for (int c=0;c<GO;c++) b2r[c] = b2[c];
    __shared__ uint32 hsP[32];
    for (int r=0;r<4;r++){
        int bn = blockIdx.x*4 + r;
        int b = bn/NN, n = bn - b*NN;
        // ---- GAT2 aggregation: single online pass ----
        int base = offs[n], deg = offs[n+1]-base;
        float sdd = s2dst[bn];
        float m = -1e30f, d = 0.f;
        float acc[GO];
        #pragma unroll
        for (int c=0;c<GO;c++) acc[c]=0.f;
        for (int e=lane;e<deg;e+=64){
            int s = csr[base+e];
            float sc = lrelu(s2src[b*NN+s] + sdd);
            float w;
            if (sc > m){
                float ee = __expf(m - sc);
                d *= ee;
                #pragma unroll
                for (int c=0;c<GO;c++) acc[c] *= ee;
                m = sc; w = 1.f;
            } else {
                w = __expf(sc - m);
            }
            d += w;
            const float* hr2 = h2 + (size_t)(b*NN+s)*GO;
            #pragma unroll
            for (int c=0;c<GO;c++) acc[c] += w*hr2[c];
        }
        // flash-combine butterfly (broadcast: all lanes end with totals)
        #pragma unroll
        for (int st=1; st<64; st<<=1){
            float m2 = __shfl_xor(m, st);
            float d2 = __shfl_xor(d, st);
            float mn = fmaxf(m, m2);
            float e1 = __expf(m - mn), e2 = __expf(m2 - mn);
            d = d*e1 + d2*e2;
            #pragma unroll
            for (int c=0;c<GO;c++){
                float a2 = __shfl_xor(acc[c], st);
                acc[c] = acc[c]*e1 + a2*e2;
            }
            m = mn;
        }
        float rdv = 1.f / d;
        // all lanes now hold g[c] = acc[c]*rdv + b2r[c]
        float xnv = xn[bn];
        const float* fp = feat + ((size_t)(b*20 + 8 + t)*NN + n)*FEAT;
        float ft[FEAT];
        #pragma unroll
        for (int k=0;k<FEAT;k++) ft[k] = fp[k];
        hf2 gx[14];
        #pragma unroll
        for (int p=0;p<6;p++)
            gx[p] = u2h(pkh(acc[2*p]*rdv+b2r[2*p], acc[2*p+1]*rdv+b2r[2*p+1]));
        gx[6] = u2h(pkh(acc[12]*rdv+b2r[12], xnv));
        #pragma unroll
        for (int p=0;p<6;p++)
            gx[7+p] = u2h(pkh(ft[2*p], ft[2*p+1]));
        gx[13] = u2h(pkh(ft[12], 0.f));
        // h state
        float hold = hn[bn*HID + lane];
        if (lane<32) hsP[lane] = pkh(hn[bn*HID + 2*lane], hn[bn*HID + 2*lane + 1]);
        __syncthreads();
        // ---- GRU via f16 dot2, register weights ----
        float ir = bi0, iz = bi1, inn = bi2;
        #pragma unroll
        for (int c2=0;c2<14;c2++){
            ir  = FDOT2(gx[c2], u2h(wih0[c2]), ir);
            iz  = FDOT2(gx[c2], u2h(wih1[c2]), iz);
            inn = FDOT2(gx[c2], u2h(wih2[c2]), inn);
        }
        float hr = bh0, hz = bh1, hnv = bh2;
        #pragma unroll
        for (int j2=0;j2<32;j2++){
            hf2 hv = u2h(hsP[j2]);
            hr  = FDOT2(hv, u2h(whh0[j2]), hr);
            hz  = FDOT2(hv, u2h(whh1[j2]), hz);
            hnv = FDOT2(hv, u2h(whh2[j2]), hnv);
        }
        float rg = 1.f/(1.f+__expf(-(ir+hr)));
        float zg = 1.f/(1.f+__expf(-(iz+hz)));
        float nv = tanhf(inn + rg*hnv);
        float hnew = (1.f - zg)*nv + zg*hold;
        hn[bn*HID+lane] = hnew;
        float xv = hnew * fw;
        #pragma unroll
        for (int mm=1;mm<64;mm<<=1) xv += __shfl_xor(xv,mm);
        float res = xv + fb;    // all lanes have it
        if (lane==0){
            xn[bn] = res;
            out[(b*TPRED + t)*NN + n] = res;
        }
        // ---- score + pack for step t+1 ----
        if (!last){
            const float* fp2 = feat + ((size_t)(b*20 + 9 + t)*NN + n)*FEAT;
            if (lane < 16){
                int h = lane & 7;
                const float* Wa = (lane<8) ? Wsrc : Wdst;
                float s = res * Wa[h];
                #pragma unroll
                for (int k=1;k<14;k++) s += fp2[k-1]*Wa[k*8+h];
                if (lane<8) ssrc[bn*8+h] = s; else sdst[bn*8+h] = s;
            } else if (lane < 23){
                int p = lane - 16;
                float lo = (p==0) ? res : fp2[2*p-1];
                float hi = fp2[2*p];
                xpk[bn*8+p] = pack2(lo, hi);
            } else if (lane == 23){
                xpk[bn*8+7] = 0u;
            }
        }
        __syncthreads();
    }
}

// ---------------- host ----------------

extern "C" void kernel_launch(void* const* d_in, const int* in_sizes, int n_in,
                              void* d_out, int out_size, void* d_ws, size_t ws_size,
                              hipStream_t stream){
    const float* pm25 = (const float*)d_in[0];
    const float* feat = (const float*)d_in[1];
    const int*   ei   = (const int*)  d_in[2];
    const float* W1   = (const float*)d_in[3];
    const float* a1s  = (const float*)d_in[4];
    const float* a1d  = (const float*)d_in[5];
    const float* b1   = (const float*)d_in[6];
    const float* W2   = (const float*)d_in[7];
    const float* a2s  = (const float*)d_in[8];
    const float* a2d  = (const float*)d_in[9];
    const float* b2   = (const float*)d_in[10];
    const float* Wih  = (const float*)d_in[11];
    const float* Whh  = (const float*)d_in[12];
    const float* bih  = (const float*)d_in[13];
    const float* bhh  = (const float*)d_in[14];
    const float* fcw  = (const float*)d_in[15];
    const float* fcb  = (const float*)d_in[16];
    float* out = (float*)d_out;

    float* f = (float*)d_ws;
    size_t o = 0;
    float* ssrc1 = f+o; o += (size_t)BB*NN*8;
    float* sdst1 = f+o; o += (size_t)BB*NN*8;
    uint32* aggP = (uint32*)(f+o); o += (size_t)BB*NN*64;  // packed f16 agg
    float* h2    = f+o; o += (size_t)BB*NN*GO + 8;
    float* s2s   = f+o; o += (size_t)BB*NN;
    float* s2d   = f+o; o += (size_t)BB*NN;
    float* hn    = f+o; o += (size_t)BB*NN*HID;
    float* xn    = f+o; o += (size_t)BB*NN;
    float* Wsrc  = f+o; o += INDIM*8;
    float* Wdst  = f+o; o += INDIM*8;
    uint32* xpk  = (uint32*)(f+o); o += (size_t)BB*NN*8;
    uint32* w1pk = (uint32*)(f+o); o += (size_t)C1*8;      // 64KB f16 pairs
    uint32* w2pk = (uint32*)(f+o); o += (size_t)(C1/2)*16; // 64KB f16 pairs
    uint32* WihP = (uint32*)(f+o); o += 192*14;
    uint32* WhhP = (uint32*)(f+o); o += 192*32;
    int* ibase  = (int*)(f+o);
    int* count  = ibase;
    int* cursor = ibase + NN;
    int* offs   = ibase + 2*NN;
    int* csr    = ibase + 2*NN + NN + 1;

    k_prep  <<<204, 256,0,stream>>>(W1, a1s, a1d, W2, a2s, a2d, Wih, Whh,
                                    Wsrc, Wdst, w1pk, w2pk, WihP, WhhP);
    k_init  <<<2000,256,0,stream>>>(pm25, feat, Wsrc, Wdst, hn, xn, count,
                                    ssrc1, sdst1, xpk);
    k_count <<<67,  256,0,stream>>>(ei, count);
    k_scan  <<<1,  1024,0,stream>>>(count, offs, cursor);
    k_fill  <<<67,  256,0,stream>>>(ei, cursor, csr);

    for (int t=0; t<TPRED; t++){
        k_agg14 <<<8000, 64,0,stream>>>(xpk, ssrc1, sdst1, offs, csr, aggP);
        k_expand<<<512, 256,0,stream>>>(aggP, w1pk, w2pk, b1, h2, s2s, s2d);
        k_tail  <<<2000, 64,0,stream>>>(t, (t==TPRED-1)?1:0, feat, offs, csr,
                                        h2, s2s, s2d, b2,
                                        WihP, WhhP, bih, bhh, fcw, fcb, Wsrc, Wdst,
                                        hn, xn, out, ssrc1, sdst1, xpk);
    }
}